// Round 1
// baseline (789.506 us; speedup 1.0000x reference)
//
#include <hip/hip_runtime.h>
#include <hip/hip_bf16.h>
#include <cstdint>
#include <cstddef>

// MultiHeadAttention: B=4, T=2048, D=1024, H=16, dh=64, fp32 in/out.
// Pipeline: [qkv_gemm: X@Wqkv^T -> Q,K (bf16 [B,H,T,64]), Vt (bf16 [B,H,64,T])]
//           [attn: flash attention -> ctx bf16 [B,T,1024]]
//           [out_gemm: ctx@Wout^T + b -> fp32 out]

#define SEQ 2048
#define NTOK 8192        // B*T
#define DM 1024
#define NQKV 3072

typedef __attribute__((ext_vector_type(8))) short bf16x8;
typedef __attribute__((ext_vector_type(4))) short bf16x4;
typedef __attribute__((ext_vector_type(4))) float f32x4;

static __device__ __forceinline__ short f2bf(float f) {
  union { float f; uint32_t u; } v; v.f = f;
  uint32_t r = v.u + 0x7fffu + ((v.u >> 16) & 1u);
  return (short)(r >> 16);
}

// ---------------- Kernel 1: QKV projection GEMM ----------------
// C[8192,3072] = X[8192,1024] @ W[3072,1024]^T + bias
// block tile 128x128, BK=64, 4 waves in 2x2, each wave 64x64 (4x4 MFMA tiles)
__global__ __launch_bounds__(256, 2)
void qkv_gemm(const float* __restrict__ X, const float* __restrict__ W,
              const float* __restrict__ bias,
              short* __restrict__ Q, short* __restrict__ K,
              short* __restrict__ Vt) {
  __shared__ short As[128][80];   // row stride 160B: 16B-aligned for ds_read_b128
  __shared__ short Bs[128][80];
  const int tid  = threadIdx.x;
  const int m0   = blockIdx.x * 128;
  const int n0   = blockIdx.y * 128;
  const int lane = tid & 63;
  const int w    = tid >> 6;
  const int wm   = (w >> 1) * 64, wn = (w & 1) * 64;
  const int l15  = lane & 15, quad = lane >> 4;
  const int tr   = tid >> 4, tc = (tid & 15) << 2;   // staging: 16 rows/pass, 4 floats/thread

  f32x4 acc[4][4];
  for (int i = 0; i < 4; i++)
    for (int j = 0; j < 4; j++) acc[i][j] = (f32x4)0.0f;

  for (int k0 = 0; k0 < DM; k0 += 64) {
    for (int rr = 0; rr < 128; rr += 16) {
      float4 a = *(const float4*)&X[(size_t)(m0 + rr + tr) * DM + k0 + tc];
      float4 b = *(const float4*)&W[(size_t)(n0 + rr + tr) * DM + k0 + tc];
      bf16x4 ap = { f2bf(a.x), f2bf(a.y), f2bf(a.z), f2bf(a.w) };
      bf16x4 bp = { f2bf(b.x), f2bf(b.y), f2bf(b.z), f2bf(b.w) };
      *(bf16x4*)&As[rr + tr][tc] = ap;
      *(bf16x4*)&Bs[rr + tr][tc] = bp;
    }
    __syncthreads();
    for (int ks = 0; ks < 64; ks += 32) {
      bf16x8 af[4], bfr[4];
      for (int i = 0; i < 4; i++)
        af[i] = *(const bf16x8*)&As[wm + i * 16 + l15][ks + quad * 8];
      for (int j = 0; j < 4; j++)
        bfr[j] = *(const bf16x8*)&Bs[wn + j * 16 + l15][ks + quad * 8];
      for (int i = 0; i < 4; i++)
        for (int j = 0; j < 4; j++)
          acc[i][j] = __builtin_amdgcn_mfma_f32_16x16x32_bf16(af[i], bfr[j], acc[i][j], 0, 0, 0);
    }
    __syncthreads();
  }

  // Epilogue. Feature f = s*1024 + h*64 + d (s in {0:Q,1:K,2:V}); token m = b*2048+t.
  const int qkv = n0 >> 10;   // tile lies entirely within one of Q/K/V (1024 % 128 == 0)
  for (int i = 0; i < 4; i++) {
    const int m = m0 + wm + i * 16 + quad * 4;      // token for reg r: m + r
    const int bb = m >> 11, t = m & 2047;           // t aligned to 4
    for (int j = 0; j < 4; j++) {
      const int f  = n0 + wn + j * 16 + l15;
      const int fi = f & 1023;
      const int h  = fi >> 6, d = fi & 63;
      const float bv = bias[f];
      if (qkv == 2) {
        bf16x4 pk = { f2bf(acc[i][j][0] + bv), f2bf(acc[i][j][1] + bv),
                      f2bf(acc[i][j][2] + bv), f2bf(acc[i][j][3] + bv) };
        *(bf16x4*)&Vt[((size_t)(bb * 16 + h) * 64 + d) * SEQ + t] = pk;
      } else {
        short* dst = (qkv == 0) ? Q : K;
        size_t base = ((size_t)(bb * 16 + h) * SEQ + t) * 64 + d;
        for (int r = 0; r < 4; r++)
          dst[base + (size_t)r * 64] = f2bf(acc[i][j][r] + bv);
      }
    }
  }
}

// ---------------- Kernel 2: flash attention ----------------
// grid (T/64, B*H); 4 waves/block, each wave owns 16 q-rows; Tk tiles of 64.
__global__ __launch_bounds__(256, 2)
void attn(const short* __restrict__ Q, const short* __restrict__ K,
          const short* __restrict__ Vt, short* __restrict__ ctx) {
  __shared__ short Ps[4][16][80];   // per-wave P tile (C-layout -> A-layout round trip)
  const int tid  = threadIdx.x;
  const int w    = tid >> 6, lane = tid & 63;
  const int l15  = lane & 15, quad = lane >> 4;
  const int bh   = blockIdx.y;
  const int qr   = blockIdx.x * 64 + w * 16;        // wave's q-row base
  const size_t qkbase = (size_t)bh * SEQ * 64;
  const size_t vbase  = (size_t)bh * 64 * SEQ;

  bf16x8 qf[2];
  for (int ks = 0; ks < 2; ks++)
    qf[ks] = *(const bf16x8*)&Q[qkbase + (size_t)(qr + l15) * 64 + ks * 32 + quad * 8];

  f32x4 O[4];
  for (int i = 0; i < 4; i++) O[i] = (f32x4)0.0f;
  float mrow[4], lrow[4];
  for (int r = 0; r < 4; r++) { mrow[r] = -1e30f; lrow[r] = 0.0f; }

  for (int k0 = 0; k0 < SEQ; k0 += 64) {
    // S = (Q K^T) * 0.125 ; S-tile 16x64 in C-layout (4 n-tiles)
    f32x4 S[4];
    for (int nt = 0; nt < 4; nt++) {
      S[nt] = (f32x4)0.0f;
      for (int ks = 0; ks < 2; ks++) {
        bf16x8 kf = *(const bf16x8*)&K[qkbase + (size_t)(k0 + nt * 16 + l15) * 64 + ks * 32 + quad * 8];
        S[nt] = __builtin_amdgcn_mfma_f32_16x16x32_bf16(qf[ks], kf, S[nt], 0, 0, 0);
      }
    }
    // online softmax per row (rows of this wave live at quad*4+r, cols across 16 lanes)
    float alpha[4];
    for (int r = 0; r < 4; r++) {
      float mx = -1e30f;
      for (int nt = 0; nt < 4; nt++) { S[nt][r] *= 0.125f; mx = fmaxf(mx, S[nt][r]); }
      for (int off = 1; off < 16; off <<= 1) mx = fmaxf(mx, __shfl_xor(mx, off, 16));
      float mnew = fmaxf(mrow[r], mx);
      alpha[r] = __expf(mrow[r] - mnew);
      float sm = 0.0f;
      for (int nt = 0; nt < 4; nt++) {
        float p = __expf(S[nt][r] - mnew);
        S[nt][r] = p; sm += p;
      }
      for (int off = 1; off < 16; off <<= 1) sm += __shfl_xor(sm, off, 16);
      lrow[r] = lrow[r] * alpha[r] + sm;
      mrow[r] = mnew;
    }
    // P (C-layout) -> LDS bf16 ; rescale O
    for (int nt = 0; nt < 4; nt++) {
      for (int r = 0; r < 4; r++)
        Ps[w][quad * 4 + r][nt * 16 + l15] = f2bf(S[nt][r]);
      for (int r = 0; r < 4; r++) O[nt][r] *= alpha[r];
    }
    // O += P @ V   (A-frag from LDS, B-frag contiguous from Vt)
    for (int ks = 0; ks < 2; ks++) {
      bf16x8 pf = *(const bf16x8*)&Ps[w][l15][ks * 32 + quad * 8];
      for (int nt = 0; nt < 4; nt++) {
        bf16x8 vf = *(const bf16x8*)&Vt[vbase + (size_t)(nt * 16 + l15) * SEQ + k0 + ks * 32 + quad * 8];
        O[nt] = __builtin_amdgcn_mfma_f32_16x16x32_bf16(pf, vf, O[nt], 0, 0, 0);
      }
    }
  }

  // ctx[b][t][h*64+d] bf16
  const int bb = bh >> 4, h = bh & 15;
  for (int nt = 0; nt < 4; nt++)
    for (int r = 0; r < 4; r++) {
      int t = qr + quad * 4 + r;
      ctx[(size_t)(bb * SEQ + t) * DM + h * 64 + nt * 16 + l15] = f2bf(O[nt][r] / lrow[r]);
    }
}

// ---------------- Kernel 3: output projection GEMM ----------------
// Y[8192,1024] = ctx_bf16 @ out_w[1024,1024]^T + out_b  (fp32 out)
__global__ __launch_bounds__(256, 2)
void out_gemm(const short* __restrict__ Cx, const float* __restrict__ W,
              const float* __restrict__ bias, float* __restrict__ Y) {
  __shared__ short As[128][80];
  __shared__ short Bs[128][80];
  const int tid  = threadIdx.x;
  const int m0   = blockIdx.x * 128;
  const int n0   = blockIdx.y * 128;
  const int lane = tid & 63;
  const int w    = tid >> 6;
  const int wm   = (w >> 1) * 64, wn = (w & 1) * 64;
  const int l15  = lane & 15, quad = lane >> 4;
  const int tr   = tid >> 4, tc = (tid & 15) << 2;

  f32x4 acc[4][4];
  for (int i = 0; i < 4; i++)
    for (int j = 0; j < 4; j++) acc[i][j] = (f32x4)0.0f;

  for (int k0 = 0; k0 < DM; k0 += 64) {
    for (int rr = 0; rr < 128; rr += 16) {
      bf16x4 a = *(const bf16x4*)&Cx[(size_t)(m0 + rr + tr) * DM + k0 + tc];
      float4 b = *(const float4*)&W[(size_t)(n0 + rr + tr) * DM + k0 + tc];
      bf16x4 bp = { f2bf(b.x), f2bf(b.y), f2bf(b.z), f2bf(b.w) };
      *(bf16x4*)&As[rr + tr][tc] = a;
      *(bf16x4*)&Bs[rr + tr][tc] = bp;
    }
    __syncthreads();
    for (int ks = 0; ks < 64; ks += 32) {
      bf16x8 af[4], bfr[4];
      for (int i = 0; i < 4; i++)
        af[i] = *(const bf16x8*)&As[wm + i * 16 + l15][ks + quad * 8];
      for (int j = 0; j < 4; j++)
        bfr[j] = *(const bf16x8*)&Bs[wn + j * 16 + l15][ks + quad * 8];
      for (int i = 0; i < 4; i++)
        for (int j = 0; j < 4; j++)
          acc[i][j] = __builtin_amdgcn_mfma_f32_16x16x32_bf16(af[i], bfr[j], acc[i][j], 0, 0, 0);
    }
    __syncthreads();
  }

  for (int i = 0; i < 4; i++) {
    const int m = m0 + wm + i * 16 + quad * 4;
    for (int j = 0; j < 4; j++) {
      const int n = n0 + wn + j * 16 + l15;
      const float bv = bias[n];
      for (int r = 0; r < 4; r++)
        Y[(size_t)(m + r) * DM + n] = acc[i][j][r] + bv;
    }
  }
}

extern "C" void kernel_launch(void* const* d_in, const int* in_sizes, int n_in,
                              void* d_out, int out_size, void* d_ws, size_t ws_size,
                              hipStream_t stream) {
  const float* x     = (const float*)d_in[0];
  const float* qkv_w = (const float*)d_in[1];
  const float* qkv_b = (const float*)d_in[2];
  const float* out_w = (const float*)d_in[3];
  const float* out_b = (const float*)d_in[4];
  float* out = (float*)d_out;

  const size_t NBH = (size_t)4 * 16 * SEQ * 64;   // 8,388,608 elements per buffer
  short* Q   = (short*)d_ws;
  short* K   = Q + NBH;
  short* Vt  = K + NBH;
  short* ctx = Vt + NBH;

  qkv_gemm<<<dim3(64, 24), 256, 0, stream>>>(x, qkv_w, qkv_b, Q, K, Vt);
  attn<<<dim3(SEQ / 64, 64), 256, 0, stream>>>(Q, K, Vt, ctx);
  out_gemm<<<dim3(64, 8), 256, 0, stream>>>(ctx, out_w, out_b, out);
}